// Round 17
// baseline (65.113 us; speedup 1.0000x reference)
//
#include <hip/hip_runtime.h>

// Problem constants (from setup_inputs)
#define B_     2
#define NQ     16384     // B*N
#define M2     8192
#define M3     4096
#define M4     2048
#define GPAD   64        // sentinel entries after each y-row
#define GDOT_BLOCKS 7168
#define SCAT_K_BLOCKS 112   // 32+32+16+16+8+8
#define SCAT_Q_BLOCKS 64    // 32+32
#define K2_BLOCKS (GDOT_BLOCKS + SCAT_K_BLOCKS + SCAT_Q_BLOCKS)
// padded group sizes: M + 8 rows * 64 pad = M + 512
// g0:0  g1:8704  g2:17408  g3:22016  g4:26624  g5:29184  total 31744
#define PK_TOTAL 31744

// Referee model (jax/XLA, verified R4): d = (su - 2*p) + sk, left-to-right fp32.
// su/sk: elementwise square + sequential reduce, NO FMA.
// p: K=3 GEMM ascending-k FMA chain. fl(2p) exact -> fmaf(-2,p,su) form ok.
// CORRECTNESS RULE (R12 lesson): sk/su computed ONCE in build/setup, stored;
// scan consumes stored values only. Never recompute in a new context.
__device__ __forceinline__ float np_sqnorm(float x, float y, float z) {
    return __fadd_rn(__fadd_rn(__fmul_rn(x, x), __fmul_rn(y, y)), __fmul_rn(z, z));
}
__device__ __forceinline__ float ref_dist(float su, float ux, float uy, float uz,
                                          float kx, float ky, float kz, float sk) {
    float p = fmaf(uz, kz, fmaf(uy, ky, __fmul_rn(ux, kx)));
    return __fadd_rn(fmaf(-2.0f, p, su), sk);
}
__device__ __forceinline__ int zbin(float z) {
    int b = (int)(z * 64.0f);
    return min(63, max(0, b));
}
__device__ __forceinline__ int ybin(float y) {
    int b = (int)(y * 8.0f);
    return min(7, max(0, b));
}
// sortable fp32 <-> uint32 (monotone bijection, handles negatives)
__device__ __forceinline__ unsigned skey32(float d) {
    int b = __float_as_int(d);
    return (unsigned)(b ^ ((b >> 31) | 0x80000000));
}
__device__ __forceinline__ float unskey32(unsigned u) {
    int m = ((int)u < 0) ? 0x80000000 : (int)0xFFFFFFFF;
    return __int_as_float((int)(u ^ (unsigned)m));
}
__device__ __forceinline__ int gpad_off(int g) {   // padded group base
    return (g < 2) ? g * 8704
         : (g < 4) ? 17408 + (g - 2) * 4608
                   : 26624 + (g - 4) * 2560;
}
// branchless sorted-top3 insert of u64 key (strict <; lex (d, orig_idx))
#define INS64(KK)                                                           \
    {                                                                       \
        unsigned long long kk_ = (KK);                                      \
        bool c0_ = kk_ < K0, c1_ = kk_ < K1, c2_ = kk_ < K2;                \
        unsigned long long n2_ = c1_ ? K1 : (c2_ ? kk_ : K2);               \
        unsigned long long n1_ = c0_ ? K0 : (c1_ ? kk_ : K1);               \
        unsigned long long n0_ = c0_ ? kk_ : K0;                            \
        K0 = n0_; K1 = n1_; K2 = n2_;                                       \
    }

// ---------------------------------------------------------------- kernel 1
// wc fold (blocks 0-1) + per-group 2D (y,z) hist + row-padded prefix +
// sentinel fill (blocks 2-9). Groups: 0,1=lvl2  2,3=lvl3  4,5=lvl4  6,7=queries.
__global__ void k_setup_v17(const float* __restrict__ w_fc, const float* __restrict__ w_cls,
                            const float* __restrict__ pts,
                            const float* __restrict__ xyz2, const float* __restrict__ xyz3,
                            const float* __restrict__ xyz4,
                            float* __restrict__ wc, int* __restrict__ bs,
                            int* __restrict__ cur, float4* __restrict__ pk) {
    __shared__ int h[512];
    __shared__ int bs2s[520];
    __shared__ int rs[8];
    __shared__ int rowbase[8];
    int bx = blockIdx.x, tid = threadIdx.x;
    if (bx < 2) {
        int c = bx * 256 + tid;
        if (c < 320) {
            float acc = 0.f;
#pragma unroll
            for (int j = 0; j < 64; ++j) acc = fmaf(w_fc[c * 64 + j], w_cls[j], acc);
            wc[c] = acc;
        }
        return;
    }
    int g = bx - 2;
    const float* src; int M;
    if (g < 2)      { src = xyz2 + g * M2 * 3;       M = M2; }
    else if (g < 4) { src = xyz3 + (g - 2) * M3 * 3; M = M3; }
    else if (g < 6) { src = xyz4 + (g - 4) * M4 * 3; M = M4; }
    else            { src = pts  + (g - 6) * 8192 * 3; M = 8192; }
    for (int i = tid; i < 512; i += 256) h[i] = 0;
    __syncthreads();
    for (int j = tid; j < M; j += 256) {
        int bin = (ybin(src[j * 3 + 1]) << 6) | zbin(src[j * 3 + 2]);
        atomicAdd(&h[bin], 1);
    }
    __syncthreads();
    if (tid < 8) { int s = 0; for (int zb = 0; zb < 64; ++zb) s += h[tid * 64 + zb]; rs[tid] = s; }
    __syncthreads();
    if (tid == 0) {
        int run = 0;
        for (int r = 0; r < 8; ++r) { rowbase[r] = run; run += rs[r] + ((g < 6) ? GPAD : 0); }
    }
    __syncthreads();
    if (tid < 8) {
        int run = rowbase[tid];
        for (int zb = 0; zb < 64; ++zb) { bs2s[tid * 65 + zb] = run; run += h[tid * 64 + zb]; }
        bs2s[tid * 65 + 64] = run;      // row end (sentinels follow)
    }
    __syncthreads();
    for (int i = tid; i < 520; i += 256) bs[g * 520 + i] = bs2s[i];
    for (int i = tid; i < 512; i += 256) cur[g * 512 + i] = bs2s[(i >> 6) * 65 + (i & 63)];
    if (g < 6) {
        int gb = gpad_off(g);
        for (int i = tid; i < 512; i += 256)
            pk[gb + bs2s[(i >> 6) * 65 + 64] + (i & 63)] =
                make_float4(1e18f, 1e18f, 1e18f, 3e36f);   // inert sentinel
    }
}

// ---------------------------------------------------------------- kernel 2
// gdot (one wave per known point) + 2D-binned scatter of known pts & queries.
// pk = [x,y,z,sk] stored; oi = orig index. Row-padded layout.
__global__ void k_build_v17(const float* __restrict__ pts,
                            const float* __restrict__ xyz2, const float* __restrict__ xyz3,
                            const float* __restrict__ xyz4,
                            const float* __restrict__ f2, const float* __restrict__ f3,
                            const float* __restrict__ f4, const float* __restrict__ wc,
                            float* __restrict__ g2, float* __restrict__ g3,
                            float* __restrict__ g4,
                            float4* __restrict__ pk, int* __restrict__ oi,
                            float4* __restrict__ uq, int* __restrict__ qmap,
                            int* __restrict__ cur) {
    int bx = blockIdx.x, tid = threadIdx.x;
    if (bx < GDOT_BLOCKS) {
        int gid  = bx * 256 + tid;
        int w    = gid >> 6;
        int lane = gid & 63;
        float v;
        if (w < 16384) {
            v = f2[(size_t)w * 64 + lane] * wc[lane];
        } else if (w < 24576) {
            size_t base = (size_t)(w - 16384) * 128;
            v = fmaf(f3[base + 64 + lane], wc[128 + lane], f3[base + lane] * wc[64 + lane]);
        } else {
            size_t base = (size_t)(w - 24576) * 128;
            v = fmaf(f4[base + 64 + lane], wc[256 + lane], f4[base + lane] * wc[192 + lane]);
        }
        for (int off = 32; off; off >>= 1) v += __shfl_down(v, off, 64);
        if (lane == 0) {
            if (w < 16384) g2[w] = v;
            else if (w < 24576) g3[w - 16384] = v;
            else g4[w - 24576] = v;
        }
        return;
    }
    bx -= GDOT_BLOCKS;
    __shared__ int cnt[512], base[512];
    for (int i = tid; i < 512; i += 256) cnt[i] = 0;
    __syncthreads();
    if (bx < SCAT_K_BLOCKS) {
        int g, j0;
        if (bx < 32)       { g = 0; j0 = bx * 256; }
        else if (bx < 64)  { g = 1; j0 = (bx - 32) * 256; }
        else if (bx < 80)  { g = 2; j0 = (bx - 64) * 256; }
        else if (bx < 96)  { g = 3; j0 = (bx - 80) * 256; }
        else if (bx < 104) { g = 4; j0 = (bx - 96) * 256; }
        else               { g = 5; j0 = (bx - 104) * 256; }
        const float* src = (g < 2) ? xyz2 + g * M2 * 3
                         : (g < 4) ? xyz3 + (g - 2) * M3 * 3
                                   : xyz4 + (g - 4) * M4 * 3;
        int gb = gpad_off(g);
        int j = j0 + tid;
        float x = src[j * 3], y = src[j * 3 + 1], z = src[j * 3 + 2];
        int bin = (ybin(y) << 6) | zbin(z);
        int off = atomicAdd(&cnt[bin], 1);
        __syncthreads();
        for (int i = tid; i < 512; i += 256) base[i] = atomicAdd(&cur[g * 512 + i], cnt[i]);
        __syncthreads();
        int slot = gb + base[bin] + off;
        pk[slot] = make_float4(x, y, z, np_sqnorm(x, y, z));
        oi[slot] = j;                          // orig index within (level,batch)
        return;
    }
    bx -= SCAT_K_BLOCKS;
    {   // query scatter (2D-sorted for locality; no pads)
        int b = bx >> 5;
        int j = (bx & 31) * 256 + tid;         // [0,8192) within batch
        const float* src = pts + (size_t)b * 8192 * 3;
        float x = src[j * 3], y = src[j * 3 + 1], z = src[j * 3 + 2];
        int bin = (ybin(y) << 6) | zbin(z);
        int g = 6 + b;
        int off = atomicAdd(&cnt[bin], 1);
        __syncthreads();
        for (int i = tid; i < 512; i += 256) base[i] = atomicAdd(&cur[g * 512 + i], cnt[i]);
        __syncthreads();
        int slot = b * 8192 + base[bin] + off;
        uq[slot]   = make_float4(x, y, z, np_sqnorm(x, y, z));
        qmap[slot] = b * 8192 + j;             // orig global query index
    }
}

// ---------------------------------------------------------------- kernel 3
// FOUR queries per wave: 16-lane groups (sq = wid*4 + (lane>>4), l = lane&15).
// Butterflies/extracts use xor offsets 1..8 (aligned 16-groups closed under
// xor<16). Per level & group: T-phase over own row z+-1 (values-only triple,
// 4-stage butterfly -> certified T >= referee d3), 2D-window scan (per-row
// unconditional padded reads, stride 16, branchless private u64 lex top-3),
// 3x extract-min group merge. Fixed per-query costs amortized over 4 queries.
// Semantics identical to R15/R16 (same candidate sets, keys, stable ties).
__launch_bounds__(256)
__global__ void k_scan_v17(const float4* __restrict__ pk, const int* __restrict__ oi,
                           const float4* __restrict__ uq, const int* __restrict__ qmap,
                           const int* __restrict__ bs,
                           const float* __restrict__ g2, const float* __restrict__ g3,
                           const float* __restrict__ g4,
                           float* __restrict__ out) {
    int wid  = blockIdx.x * 4 + (threadIdx.x >> 6);
    int lane = threadIdx.x & 63;
    int l    = lane & 15;                  // lane within 16-group
    int sq   = wid * 4 + (lane >> 4);      // sorted query id (group-uniform)
    int b    = sq >> 13;

    float4 u = uq[sq];
    float ux = u.x, uy = u.y, uz = u.z, suq = u.w;

    double acc = 0.0;

#pragma unroll 1
    for (int lvl = 0; lvl < 3; ++lvl) {
        int gb; const float* gl;
        if (lvl == 0)      { gb = b * 8704;          gl = g2 + b * M2; }
        else if (lvl == 1) { gb = 17408 + b * 4608;  gl = g3 + b * M3; }
        else               { gb = 26624 + b * 2560;  gl = g4 + b * M4; }
        const float4* pkg = pk + gb;
        const int*    oig = oi + gb;
        const int*    bsg = bs + (lvl * 2 + b) * 520;

        // ---- T phase: own row, z-bins [zbq-1, zbq+1] (contiguous range)
        int ybq = ybin(uy), zbq = zbin(uz);
        int ztlo = max(0, zbq - 1), zthi = min(63, zbq + 1);
        int S0 = bsg[ybq * 65 + ztlo], E0 = bsg[ybq * 65 + zthi + 1];
        float a0 = 3e38f, a1 = 3e38f, a2 = 3e38f;
        {
            int rounds0 = (E0 - S0 + 15) >> 4;
            const float4* pp = pkg + S0 + l;
            for (int r = 0; r < rounds0; ++r, pp += 16) {
                float4 kv = *pp;
                float d = ref_dist(suq, ux, uy, uz, kv.x, kv.y, kv.z, kv.w);
                float m1 = __builtin_amdgcn_fmed3f(d, a0, a1);
                float m2 = __builtin_amdgcn_fmed3f(d, a1, a2);
                a0 = fminf(d, a0); a1 = m1; a2 = m2;
            }
        }
#pragma unroll
        for (int off = 1; off < 16; off <<= 1) {
            float b0 = __shfl_xor(a0, off, 64);
            float b1 = __shfl_xor(a1, off, 64);
            float b2 = __shfl_xor(a2, off, 64);
            float m1 = __builtin_amdgcn_fmed3f(b0, a0, a1);
            float m2 = __builtin_amdgcn_fmed3f(b0, a1, a2);
            a0 = fminf(b0, a0); a1 = m1; a2 = m2;
            m1 = __builtin_amdgcn_fmed3f(b1, a0, a1);
            m2 = __builtin_amdgcn_fmed3f(b1, a1, a2);
            a0 = fminf(b1, a0); a1 = m1; a2 = m2;
            m1 = __builtin_amdgcn_fmed3f(b2, a0, a1);
            m2 = __builtin_amdgcn_fmed3f(b2, a1, a2);
            a0 = fminf(b2, a0); a1 = m1; a2 = m2;
        }
        float T = a2;   // group-uniform certified upper bound on referee d3

        // ---- 2D window: rows [ylo,yhi] x z-bins [zlo,zhi], s = sqrt(T+1e-5)
        float s  = sqrtf(__fadd_rn(T, 1e-5f));
        int ylo = min(7,  (int)fmaxf((uy - s) * 8.0f, 0.0f));
        int yhi = (int)fminf((uy + s) * 8.0f, 7.0f);
        int zlo = min(63, (int)fmaxf((uz - s) * 64.0f, 0.0f));
        int zhi = (int)fminf((uz + s) * 64.0f, 63.0f);

        int tbits = __float_as_int(T);
        float Tp = (T > 0.0f) ? __int_as_float(tbits + 1)
                 : (T < 0.0f) ? __int_as_float(tbits - 1) : 1e-45f;
        unsigned long long PAD = ((unsigned long long)skey32(Tp) << 32) | 0xFFFFFFFFull;
        unsigned long long K0 = PAD, K1 = PAD, K2 = PAD;

        // ---- per-row branchless private scan (row pads make overreads inert)
        for (int yb = ylo; yb <= yhi; ++yb) {
            int S = bsg[yb * 65 + zlo], E = bsg[yb * 65 + zhi + 1];
            int rounds = (E - S + 15) >> 4;
            const float4* pp = pkg + S + l;
            const int*    po = oig + S + l;
            for (int r = 0; r < rounds; ++r, pp += 16, po += 16) {
                float4 kv = *pp;
                int    o  = *po;
                float d = ref_dist(suq, ux, uy, uz, kv.x, kv.y, kv.z, kv.w);
                unsigned long long kk =
                    ((unsigned long long)skey32(d) << 32) | (unsigned)o;
                INS64(kk);
            }
        }

        // ---- extract 3 group-minima (u64 butterfly-min + removal), sorted
        unsigned long long m0, m1, m2;
#pragma unroll
        for (int e = 0; e < 3; ++e) {
            unsigned long long mn = K0;
#pragma unroll
            for (int off = 1; off < 16; off <<= 1) {
                unsigned long long o = __shfl_xor(mn, off, 64);
                mn = (o < mn) ? o : mn;
            }
            if (e == 0) m0 = mn; else if (e == 1) m1 = mn; else m2 = mn;
            bool hit = (K0 == mn);              // exactly one lane (keys unique)
            K0 = hit ? K1 : K0;
            K1 = hit ? K2 : K1;
            K2 = hit ? 0xFFFFFFFFFFFFFFFFull : K2;
        }

        // ---- referee weights (bit-exact fp32) + f64 g-fold (group-uniform)
        float d0 = unskey32((unsigned)(m0 >> 32));
        float d1 = unskey32((unsigned)(m1 >> 32));
        float d2 = unskey32((unsigned)(m2 >> 32));
        int i0 = (int)(m0 & 0xFFFFFFFFull);
        int i1 = (int)(m1 & 0xFFFFFFFFull);
        int i2 = (int)(m2 & 0xFFFFFFFFull);
        float r0 = __fdiv_rn(1.0f, __fadd_rn(d0, 1e-8f));
        float r1 = __fdiv_rn(1.0f, __fadd_rn(d1, 1e-8f));
        float r2 = __fdiv_rn(1.0f, __fadd_rn(d2, 1e-8f));
        float sw = __fadd_rn(__fadd_rn(r0, r1), r2);
        float w0 = __fdiv_rn(r0, sw), w1 = __fdiv_rn(r1, sw), w2 = __fdiv_rn(r2, sw);
        acc += (double)w0 * (double)gl[i0] + (double)w1 * (double)gl[i1]
             + (double)w2 * (double)gl[i2];
    }
    if (l == 0) out[qmap[sq]] = (float)acc;
}

// ---------------------------------------------------------------- launch
extern "C" void kernel_launch(void* const* d_in, const int* in_sizes, int n_in,
                              void* d_out, int out_size, void* d_ws, size_t ws_size,
                              hipStream_t stream) {
    const float* pts   = (const float*)d_in[0];
    const float* xyz2  = (const float*)d_in[1];
    const float* feat2 = (const float*)d_in[2];
    const float* xyz3  = (const float*)d_in[3];
    const float* feat3 = (const float*)d_in[4];
    const float* xyz4  = (const float*)d_in[5];
    const float* feat4 = (const float*)d_in[6];
    const float* w_fc  = (const float*)d_in[7];
    const float* w_cls = (const float*)d_in[8];
    float* out = (float*)d_out;

    // workspace layout (~1.15 MB)
    float4* pk   = (float4*)d_ws;          // PK_TOTAL float4 (row-padded groups)
    float4* uq   = pk + PK_TOTAL;          // 16384 float4
    float*  g2   = (float*)(uq + 16384);   // 16384
    float*  g3   = g2 + 16384;             // 8192
    float*  g4   = g3 + 8192;              // 4096
    float*  wc   = g4 + 4096;              // 320
    int*    oi   = (int*)(wc + 320);       // PK_TOTAL
    int*    qmap = oi + PK_TOTAL;          // 16384
    int*    bs   = qmap + 16384;           // 8*520
    int*    cur  = bs + 8 * 520;           // 8*512

    k_setup_v17<<<10, 256, 0, stream>>>(w_fc, w_cls, pts, xyz2, xyz3, xyz4,
                                        wc, bs, cur, pk);
    k_build_v17<<<K2_BLOCKS, 256, 0, stream>>>(pts, xyz2, xyz3, xyz4,
                                               feat2, feat3, feat4, wc,
                                               g2, g3, g4, pk, oi, uq, qmap, cur);
    k_scan_v17<<<1024, 256, 0, stream>>>(pk, oi, uq, qmap, bs, g2, g3, g4, out);
}

// Round 18
// 46.764 us; speedup vs baseline: 1.3924x; 1.3924x over previous
//
#include <hip/hip_runtime.h>

// Problem constants (from setup_inputs)
#define B_     2
#define NQ     16384     // B*N
#define M2     8192
#define M3     4096
#define M4     2048
#define GPAD   64        // sentinel entries after each y-row
#define GDOT_BLOCKS 7168
#define SCAT_K_BLOCKS 112   // 32+32+16+16+8+8
#define SCAT_Q_BLOCKS 64    // 32+32
#define K2_BLOCKS (GDOT_BLOCKS + SCAT_K_BLOCKS + SCAT_Q_BLOCKS)
// padded group sizes: M + 8 rows * 64 pad = M + 512
// g0:0  g1:8704  g2:17408  g3:22016  g4:26624  g5:29184  total 31744
#define PK_TOTAL 31744
#define NSCANW (8192*3)     // (query-pair, level) waves

// Referee model (jax/XLA, verified R4): d = (su - 2*p) + sk, left-to-right fp32.
// su/sk: elementwise square + sequential reduce, NO FMA.
// p: K=3 GEMM ascending-k FMA chain. fl(2p) exact -> fmaf(-2,p,su) form ok.
// CORRECTNESS RULE (R12 lesson): sk/su computed ONCE in build/setup, stored;
// scan consumes stored values only. Never recompute in a new context.
__device__ __forceinline__ float np_sqnorm(float x, float y, float z) {
    return __fadd_rn(__fadd_rn(__fmul_rn(x, x), __fmul_rn(y, y)), __fmul_rn(z, z));
}
__device__ __forceinline__ float ref_dist(float su, float ux, float uy, float uz,
                                          float kx, float ky, float kz, float sk) {
    float p = fmaf(uz, kz, fmaf(uy, ky, __fmul_rn(ux, kx)));
    return __fadd_rn(fmaf(-2.0f, p, su), sk);
}
__device__ __forceinline__ int zbin(float z) {
    int b = (int)(z * 64.0f);
    return min(63, max(0, b));
}
__device__ __forceinline__ int ybin(float y) {
    int b = (int)(y * 8.0f);
    return min(7, max(0, b));
}
// sortable fp32 <-> uint32 (monotone bijection, handles negatives)
__device__ __forceinline__ unsigned skey32(float d) {
    int b = __float_as_int(d);
    return (unsigned)(b ^ ((b >> 31) | 0x80000000));
}
__device__ __forceinline__ float unskey32(unsigned u) {
    int m = ((int)u < 0) ? 0x80000000 : (int)0xFFFFFFFF;
    return __int_as_float((int)(u ^ (unsigned)m));
}
__device__ __forceinline__ int gpad_off(int g) {   // padded group base
    return (g < 2) ? g * 8704
         : (g < 4) ? 17408 + (g - 2) * 4608
                   : 26624 + (g - 4) * 2560;
}
// branchless sorted-top3 insert of u64 key (strict <; lex (d, orig_idx))
#define INS64(KK)                                                           \
    {                                                                       \
        unsigned long long kk_ = (KK);                                      \
        bool c0_ = kk_ < K0, c1_ = kk_ < K1, c2_ = kk_ < K2;                \
        unsigned long long n2_ = c1_ ? K1 : (c2_ ? kk_ : K2);               \
        unsigned long long n1_ = c0_ ? K0 : (c1_ ? kk_ : K1);               \
        unsigned long long n0_ = c0_ ? kk_ : K0;                            \
        K0 = n0_; K1 = n1_; K2 = n2_;                                       \
    }

// ---------------------------------------------------------------- kernel 1
// wc fold (blocks 0-1) + per-group 2D (y,z) hist + row-padded prefix +
// sentinel fill (blocks 2-9). Groups: 0,1=lvl2  2,3=lvl3  4,5=lvl4  6,7=queries.
__global__ void k_setup_v18(const float* __restrict__ w_fc, const float* __restrict__ w_cls,
                            const float* __restrict__ pts,
                            const float* __restrict__ xyz2, const float* __restrict__ xyz3,
                            const float* __restrict__ xyz4,
                            float* __restrict__ wc, int* __restrict__ bs,
                            int* __restrict__ cur, float4* __restrict__ pk) {
    __shared__ int h[512];
    __shared__ int bs2s[520];
    __shared__ int rs[8];
    __shared__ int rowbase[8];
    int bx = blockIdx.x, tid = threadIdx.x;
    if (bx < 2) {
        int c = bx * 256 + tid;
        if (c < 320) {
            float acc = 0.f;
#pragma unroll
            for (int j = 0; j < 64; ++j) acc = fmaf(w_fc[c * 64 + j], w_cls[j], acc);
            wc[c] = acc;
        }
        return;
    }
    int g = bx - 2;
    const float* src; int M;
    if (g < 2)      { src = xyz2 + g * M2 * 3;       M = M2; }
    else if (g < 4) { src = xyz3 + (g - 2) * M3 * 3; M = M3; }
    else if (g < 6) { src = xyz4 + (g - 4) * M4 * 3; M = M4; }
    else            { src = pts  + (g - 6) * 8192 * 3; M = 8192; }
    for (int i = tid; i < 512; i += 256) h[i] = 0;
    __syncthreads();
    for (int j = tid; j < M; j += 256) {
        int bin = (ybin(src[j * 3 + 1]) << 6) | zbin(src[j * 3 + 2]);
        atomicAdd(&h[bin], 1);
    }
    __syncthreads();
    if (tid < 8) { int s = 0; for (int zb = 0; zb < 64; ++zb) s += h[tid * 64 + zb]; rs[tid] = s; }
    __syncthreads();
    if (tid == 0) {
        int run = 0;
        for (int r = 0; r < 8; ++r) { rowbase[r] = run; run += rs[r] + ((g < 6) ? GPAD : 0); }
    }
    __syncthreads();
    if (tid < 8) {
        int run = rowbase[tid];
        for (int zb = 0; zb < 64; ++zb) { bs2s[tid * 65 + zb] = run; run += h[tid * 64 + zb]; }
        bs2s[tid * 65 + 64] = run;      // row end (sentinels follow)
    }
    __syncthreads();
    for (int i = tid; i < 520; i += 256) bs[g * 520 + i] = bs2s[i];
    for (int i = tid; i < 512; i += 256) cur[g * 512 + i] = bs2s[(i >> 6) * 65 + (i & 63)];
    if (g < 6) {
        int gb = gpad_off(g);
        for (int i = tid; i < 512; i += 256)
            pk[gb + bs2s[(i >> 6) * 65 + 64] + (i & 63)] =
                make_float4(1e18f, 1e18f, 1e18f, 3e36f);   // inert sentinel
    }
}

// ---------------------------------------------------------------- kernel 2
// gdot (one wave per known point) + 2D-binned scatter of known pts & queries.
// pk = [x,y,z,sk] stored; oi = orig index. Row-padded layout.
__global__ void k_build_v18(const float* __restrict__ pts,
                            const float* __restrict__ xyz2, const float* __restrict__ xyz3,
                            const float* __restrict__ xyz4,
                            const float* __restrict__ f2, const float* __restrict__ f3,
                            const float* __restrict__ f4, const float* __restrict__ wc,
                            float* __restrict__ g2, float* __restrict__ g3,
                            float* __restrict__ g4,
                            float4* __restrict__ pk, int* __restrict__ oi,
                            float4* __restrict__ uq, int* __restrict__ qmap,
                            int* __restrict__ cur) {
    int bx = blockIdx.x, tid = threadIdx.x;
    if (bx < GDOT_BLOCKS) {
        int gid  = bx * 256 + tid;
        int w    = gid >> 6;
        int lane = gid & 63;
        float v;
        if (w < 16384) {
            v = f2[(size_t)w * 64 + lane] * wc[lane];
        } else if (w < 24576) {
            size_t base = (size_t)(w - 16384) * 128;
            v = fmaf(f3[base + 64 + lane], wc[128 + lane], f3[base + lane] * wc[64 + lane]);
        } else {
            size_t base = (size_t)(w - 24576) * 128;
            v = fmaf(f4[base + 64 + lane], wc[256 + lane], f4[base + lane] * wc[192 + lane]);
        }
        for (int off = 32; off; off >>= 1) v += __shfl_down(v, off, 64);
        if (lane == 0) {
            if (w < 16384) g2[w] = v;
            else if (w < 24576) g3[w - 16384] = v;
            else g4[w - 24576] = v;
        }
        return;
    }
    bx -= GDOT_BLOCKS;
    __shared__ int cnt[512], base[512];
    for (int i = tid; i < 512; i += 256) cnt[i] = 0;
    __syncthreads();
    if (bx < SCAT_K_BLOCKS) {
        int g, j0;
        if (bx < 32)       { g = 0; j0 = bx * 256; }
        else if (bx < 64)  { g = 1; j0 = (bx - 32) * 256; }
        else if (bx < 80)  { g = 2; j0 = (bx - 64) * 256; }
        else if (bx < 96)  { g = 3; j0 = (bx - 80) * 256; }
        else if (bx < 104) { g = 4; j0 = (bx - 96) * 256; }
        else               { g = 5; j0 = (bx - 104) * 256; }
        const float* src = (g < 2) ? xyz2 + g * M2 * 3
                         : (g < 4) ? xyz3 + (g - 2) * M3 * 3
                                   : xyz4 + (g - 4) * M4 * 3;
        int gb = gpad_off(g);
        int j = j0 + tid;
        float x = src[j * 3], y = src[j * 3 + 1], z = src[j * 3 + 2];
        int bin = (ybin(y) << 6) | zbin(z);
        int off = atomicAdd(&cnt[bin], 1);
        __syncthreads();
        for (int i = tid; i < 512; i += 256) base[i] = atomicAdd(&cur[g * 512 + i], cnt[i]);
        __syncthreads();
        int slot = gb + base[bin] + off;
        pk[slot] = make_float4(x, y, z, np_sqnorm(x, y, z));
        oi[slot] = j;                          // orig index within (level,batch)
        return;
    }
    bx -= SCAT_K_BLOCKS;
    {   // query scatter (2D-sorted for locality; no pads)
        int b = bx >> 5;
        int j = (bx & 31) * 256 + tid;         // [0,8192) within batch
        const float* src = pts + (size_t)b * 8192 * 3;
        float x = src[j * 3], y = src[j * 3 + 1], z = src[j * 3 + 2];
        int bin = (ybin(y) << 6) | zbin(z);
        int g = 6 + b;
        int off = atomicAdd(&cnt[bin], 1);
        __syncthreads();
        for (int i = tid; i < 512; i += 256) base[i] = atomicAdd(&cur[g * 512 + i], cnt[i]);
        __syncthreads();
        int slot = b * 8192 + base[bin] + off;
        uq[slot]   = make_float4(x, y, z, np_sqnorm(x, y, z));
        qmap[slot] = b * 8192 + j;             // orig global query index
    }
}

// ---------------------------------------------------------------- kernel 3
// Wave = (query-pair, ONE level): 24576 waves (3x R16's TLP), 32-lane groups
// (sq = pair*2 + (lane>>5), l = lane&31), butterflies/extracts xor 1..16.
// Per-level body identical to R16: T-phase over own row z+-1 -> certified T,
// 2D-window scan (per-row unconditional padded reads, branchless private u64
// lex top-3), 3x extract-min group merge, bit-exact fp32 weights, f64 fold.
// Writes per-level f64 partial; k_sum folds 3 partials (fixed order).
// Semantics identical to R15/R16 (same candidate sets, keys, stable ties).
__launch_bounds__(256)
__global__ void k_scan_v18(const float4* __restrict__ pk, const int* __restrict__ oi,
                           const float4* __restrict__ uq,
                           const int* __restrict__ bs,
                           const float* __restrict__ g2, const float* __restrict__ g3,
                           const float* __restrict__ g4,
                           double* __restrict__ part) {
    int wid  = blockIdx.x * 4 + (threadIdx.x >> 6);   // 0..24575
    int lane = threadIdx.x & 63;
    int l    = lane & 31;                  // lane within 32-group
    int pair = wid / 3;
    int lvl  = wid - pair * 3;
    int sq   = pair * 2 + (lane >> 5);     // sorted query id (group-uniform)
    int b    = sq >> 13;

    float4 u = uq[sq];
    float ux = u.x, uy = u.y, uz = u.z, suq = u.w;

    int gb; const float* gl;
    if (lvl == 0)      { gb = b * 8704;          gl = g2 + b * M2; }
    else if (lvl == 1) { gb = 17408 + b * 4608;  gl = g3 + b * M3; }
    else               { gb = 26624 + b * 2560;  gl = g4 + b * M4; }
    const float4* pkg = pk + gb;
    const int*    oig = oi + gb;
    const int*    bsg = bs + (lvl * 2 + b) * 520;

    // ---- T phase: own row, z-bins [zbq-1, zbq+1] (contiguous range)
    int ybq = ybin(uy), zbq = zbin(uz);
    int ztlo = max(0, zbq - 1), zthi = min(63, zbq + 1);
    int S0 = bsg[ybq * 65 + ztlo], E0 = bsg[ybq * 65 + zthi + 1];
    float a0 = 3e38f, a1 = 3e38f, a2 = 3e38f;
    {
        int rounds0 = (E0 - S0 + 31) >> 5;
        const float4* pp = pkg + S0 + l;
        for (int r = 0; r < rounds0; ++r, pp += 32) {
            float4 kv = *pp;
            float d = ref_dist(suq, ux, uy, uz, kv.x, kv.y, kv.z, kv.w);
            float m1 = __builtin_amdgcn_fmed3f(d, a0, a1);
            float m2 = __builtin_amdgcn_fmed3f(d, a1, a2);
            a0 = fminf(d, a0); a1 = m1; a2 = m2;
        }
    }
#pragma unroll
    for (int off = 1; off < 32; off <<= 1) {
        float b0 = __shfl_xor(a0, off, 64);
        float b1 = __shfl_xor(a1, off, 64);
        float b2 = __shfl_xor(a2, off, 64);
        float m1 = __builtin_amdgcn_fmed3f(b0, a0, a1);
        float m2 = __builtin_amdgcn_fmed3f(b0, a1, a2);
        a0 = fminf(b0, a0); a1 = m1; a2 = m2;
        m1 = __builtin_amdgcn_fmed3f(b1, a0, a1);
        m2 = __builtin_amdgcn_fmed3f(b1, a1, a2);
        a0 = fminf(b1, a0); a1 = m1; a2 = m2;
        m1 = __builtin_amdgcn_fmed3f(b2, a0, a1);
        m2 = __builtin_amdgcn_fmed3f(b2, a1, a2);
        a0 = fminf(b2, a0); a1 = m1; a2 = m2;
    }
    float T = a2;   // group-uniform certified upper bound on referee d3

    // ---- 2D window: rows [ylo,yhi] x z-bins [zlo,zhi], s = sqrt(T+1e-5)
    float s  = sqrtf(__fadd_rn(T, 1e-5f));
    int ylo = min(7,  (int)fmaxf((uy - s) * 8.0f, 0.0f));
    int yhi = (int)fminf((uy + s) * 8.0f, 7.0f);
    int zlo = min(63, (int)fmaxf((uz - s) * 64.0f, 0.0f));
    int zhi = (int)fminf((uz + s) * 64.0f, 63.0f);

    int tbits = __float_as_int(T);
    float Tp = (T > 0.0f) ? __int_as_float(tbits + 1)
             : (T < 0.0f) ? __int_as_float(tbits - 1) : 1e-45f;
    unsigned long long PAD = ((unsigned long long)skey32(Tp) << 32) | 0xFFFFFFFFull;
    unsigned long long K0 = PAD, K1 = PAD, K2 = PAD;

    // ---- per-row branchless private scan (row pads make overreads inert)
    for (int yb = ylo; yb <= yhi; ++yb) {
        int S = bsg[yb * 65 + zlo], E = bsg[yb * 65 + zhi + 1];
        int rounds = (E - S + 31) >> 5;
        const float4* pp = pkg + S + l;
        const int*    po = oig + S + l;
        for (int r = 0; r < rounds; ++r, pp += 32, po += 32) {
            float4 kv = *pp;
            int    o  = *po;
            float d = ref_dist(suq, ux, uy, uz, kv.x, kv.y, kv.z, kv.w);
            unsigned long long kk =
                ((unsigned long long)skey32(d) << 32) | (unsigned)o;
            INS64(kk);
        }
    }

    // ---- extract 3 group-minima (u64 butterfly-min + removal), sorted
    unsigned long long m0, m1, m2;
#pragma unroll
    for (int e = 0; e < 3; ++e) {
        unsigned long long mn = K0;
#pragma unroll
        for (int off = 1; off < 32; off <<= 1) {
            unsigned long long o = __shfl_xor(mn, off, 64);
            mn = (o < mn) ? o : mn;
        }
        if (e == 0) m0 = mn; else if (e == 1) m1 = mn; else m2 = mn;
        bool hit = (K0 == mn);              // exactly one lane (keys unique)
        K0 = hit ? K1 : K0;
        K1 = hit ? K2 : K1;
        K2 = hit ? 0xFFFFFFFFFFFFFFFFull : K2;
    }

    // ---- referee weights (bit-exact fp32) + f64 g-fold (group-uniform)
    float d0 = unskey32((unsigned)(m0 >> 32));
    float d1 = unskey32((unsigned)(m1 >> 32));
    float d2 = unskey32((unsigned)(m2 >> 32));
    int i0 = (int)(m0 & 0xFFFFFFFFull);
    int i1 = (int)(m1 & 0xFFFFFFFFull);
    int i2 = (int)(m2 & 0xFFFFFFFFull);
    float r0 = __fdiv_rn(1.0f, __fadd_rn(d0, 1e-8f));
    float r1 = __fdiv_rn(1.0f, __fadd_rn(d1, 1e-8f));
    float r2 = __fdiv_rn(1.0f, __fadd_rn(d2, 1e-8f));
    float sw = __fadd_rn(__fadd_rn(r0, r1), r2);
    float w0 = __fdiv_rn(r0, sw), w1 = __fdiv_rn(r1, sw), w2 = __fdiv_rn(r2, sw);
    double v = (double)w0 * (double)gl[i0] + (double)w1 * (double)gl[i1]
             + (double)w2 * (double)gl[i2];
    if (l == 0) part[lvl * NQ + sq] = v;
}

// ---------------------------------------------------------------- kernel 4
// Fold 3 per-level partials (fixed order -> deterministic), scatter via qmap.
__global__ void k_sum_v18(const double* __restrict__ part,
                          const int* __restrict__ qmap, float* __restrict__ out) {
    int sq = blockIdx.x * 256 + threadIdx.x;
    out[qmap[sq]] = (float)(part[sq] + part[NQ + sq] + part[2 * NQ + sq]);
}

// ---------------------------------------------------------------- launch
extern "C" void kernel_launch(void* const* d_in, const int* in_sizes, int n_in,
                              void* d_out, int out_size, void* d_ws, size_t ws_size,
                              hipStream_t stream) {
    const float* pts   = (const float*)d_in[0];
    const float* xyz2  = (const float*)d_in[1];
    const float* feat2 = (const float*)d_in[2];
    const float* xyz3  = (const float*)d_in[3];
    const float* feat3 = (const float*)d_in[4];
    const float* xyz4  = (const float*)d_in[5];
    const float* feat4 = (const float*)d_in[6];
    const float* w_fc  = (const float*)d_in[7];
    const float* w_cls = (const float*)d_in[8];
    float* out = (float*)d_out;

    // workspace layout (~1.55 MB)
    float4* pk   = (float4*)d_ws;          // PK_TOTAL float4 (row-padded groups)
    float4* uq   = pk + PK_TOTAL;          // 16384 float4
    float*  g2   = (float*)(uq + 16384);   // 16384
    float*  g3   = g2 + 16384;             // 8192
    float*  g4   = g3 + 8192;              // 4096
    float*  wc   = g4 + 4096;              // 320
    int*    oi   = (int*)(wc + 320);       // PK_TOTAL
    int*    qmap = oi + PK_TOTAL;          // 16384
    int*    bs   = qmap + 16384;           // 8*520
    int*    cur  = bs + 8 * 520;           // 8*512
    double* part = (double*)(cur + 8 * 512);  // 3*NQ doubles (8B-aligned: even word count)

    k_setup_v18<<<10, 256, 0, stream>>>(w_fc, w_cls, pts, xyz2, xyz3, xyz4,
                                        wc, bs, cur, pk);
    k_build_v18<<<K2_BLOCKS, 256, 0, stream>>>(pts, xyz2, xyz3, xyz4,
                                               feat2, feat3, feat4, wc,
                                               g2, g3, g4, pk, oi, uq, qmap, cur);
    k_scan_v18<<<NSCANW / 4, 256, 0, stream>>>(pk, oi, uq, bs, g2, g3, g4, part);
    k_sum_v18<<<64, 256, 0, stream>>>(part, qmap, out);
}